// Round 1
// baseline (143.436 us; speedup 1.0000x reference)
//
#include <hip/hip_runtime.h>
#include <math.h>

#define NQ   12
#define DIM  4096          // 2^12
#define BLK  256           // threads per block
#define NPAR 144           // LAYERS*4*NQ = 3*4*12

__device__ __forceinline__ void apply_ry(float* re, float* im, int m,
                                         float c, float s, int tid) {
    // 2048 pairs: i0 has bit m clear, i1 = i0 | m
    #pragma unroll
    for (int p = tid; p < DIM / 2; p += BLK) {
        int i0 = ((p & ~(m - 1)) << 1) | (p & (m - 1));
        int i1 = i0 | m;
        float r0 = re[i0], r1 = re[i1];
        float q0 = im[i0], q1 = im[i1];
        re[i0] = c * r0 - s * r1;
        im[i0] = c * q0 - s * q1;
        re[i1] = s * r0 + c * r1;
        im[i1] = s * q0 + c * q1;
    }
    __syncthreads();
}

__device__ __forceinline__ void apply_crx(float* re, float* im, int mc, int mt,
                                          float c, float s, int tid) {
    // only the control=1 subspace is modified: 1024 pairs
    int mlo = (mc < mt) ? mc : mt;
    int mhi = mc ^ mt ^ mlo;
    #pragma unroll
    for (int p = tid; p < DIM / 4; p += BLK) {
        int i = ((p & ~(mlo - 1)) << 1) | (p & (mlo - 1));
        i     = ((i & ~(mhi - 1)) << 1) | (i & (mhi - 1));
        int i0 = i | mc;        // control bit set, target bit 0
        int i1 = i0 | mt;       // control bit set, target bit 1
        float r0 = re[i0], r1 = re[i1];
        float q0 = im[i0], q1 = im[i1];
        // off-diagonal coefficient is -i*s  (s = sin(theta/2))
        re[i0] = c * r0 + s * q1;
        im[i0] = c * q0 - s * r1;
        re[i1] = c * r1 + s * q0;
        im[i1] = c * q1 - s * r0;
    }
    __syncthreads();
}

__global__ __launch_bounds__(BLK) void ansatz_kernel(
    const float* __restrict__ sre, const float* __restrict__ sim,
    const float* __restrict__ params, float* __restrict__ out) {

    __shared__ float re[DIM];
    __shared__ float im[DIM];
    __shared__ float cs_s[NPAR];
    __shared__ float sn_s[NPAR];

    const int b   = blockIdx.x;
    const int tid = threadIdx.x;

    // load state into LDS (coalesced)
    for (int i = tid; i < DIM; i += BLK) {
        re[i] = sre[b * DIM + i];
        im[i] = sim[b * DIM + i];
    }
    // precompute cos/sin of theta/2 for all 144 gates of this batch element
    for (int i = tid; i < NPAR; i += BLK) {
        float th = 0.5f * params[b * NPAR + i];
        float s, c;
        sincosf(th, &s, &c);
        cs_s[i] = c;
        sn_s[i] = s;
    }
    __syncthreads();

    for (int l = 0; l < 3; ++l) {
        const int base = l * 48;
        // group 0: RY on qubits 0..11
        for (int w = 0; w < NQ; ++w)
            apply_ry(re, im, 1 << (NQ - 1 - w), cs_s[base + w], sn_s[base + w], tid);
        // group 1: CRX(control=w, target=(w+1)%12) for w = 11,10,...,0 ; theta idx i = 11-w
        for (int i = 0; i < NQ; ++i) {
            int w = NQ - 1 - i;
            int t = (w + 1) % NQ;
            apply_crx(re, im, 1 << (NQ - 1 - w), 1 << (NQ - 1 - t),
                      cs_s[base + 12 + i], sn_s[base + 12 + i], tid);
        }
        // group 2: RY on qubits 0..11
        for (int w = 0; w < NQ; ++w)
            apply_ry(re, im, 1 << (NQ - 1 - w), cs_s[base + 24 + w], sn_s[base + 24 + w], tid);
        // group 3: CRX(control=w, target=(w-1)%12) for w = 11,0,1,...,10 ; theta idx i
        for (int i = 0; i < NQ; ++i) {
            int w = (i == 0) ? (NQ - 1) : (i - 1);
            int t = (w + NQ - 1) % NQ;
            apply_crx(re, im, 1 << (NQ - 1 - w), 1 << (NQ - 1 - t),
                      cs_s[base + 36 + i], sn_s[base + 36 + i], tid);
        }
    }

    // store interleaved (re, im) = reference's stack([real, imag], -1)
    float2* out2 = (float2*)out;
    for (int i = tid; i < DIM; i += BLK) {
        float2 v;
        v.x = re[i];
        v.y = im[i];
        out2[b * DIM + i] = v;
    }
}

extern "C" void kernel_launch(void* const* d_in, const int* in_sizes, int n_in,
                              void* d_out, int out_size, void* d_ws, size_t ws_size,
                              hipStream_t stream) {
    const float* sre    = (const float*)d_in[0];
    const float* sim    = (const float*)d_in[1];
    const float* params = (const float*)d_in[2];
    float* out          = (float*)d_out;

    const int B = in_sizes[0] / DIM;   // 128
    ansatz_kernel<<<B, BLK, 0, stream>>>(sre, sim, params, out);
}

// Round 2
// 91.775 us; speedup vs baseline: 1.5629x; 1.5629x over previous
//
#include <hip/hip_runtime.h>
#include <math.h>

#define NQ   12
#define DIM  4096          // 2^12 amplitudes
#define BLK  256           // threads per block; 16 complex amplitudes per thread
#define NPAR 144           // 3 layers * 4 groups * 12 qubits

// XOR swizzle on the float2 index: for any contiguous-6-bit lane-varying window
// (all rotations k), A&15 gets 4 independent lane bits -> uniform 4 lanes/bank-pair.
__device__ __forceinline__ int swz(int i) { return i ^ ((i >> 6) & 63); }

__device__ __forceinline__ int rotl12(int x, int k) {
    return ((x << k) | (x >> (12 - k))) & 4095;    // k in [0,11]; k==0 ok (x>>12==0)
}

// RY on register-local bit with mask M: 8 pairs, fully unrolled (constant indices).
template<int M>
__device__ __forceinline__ void ry_reg(float (&xr)[16], float (&xi)[16], float c, float s) {
    #pragma unroll
    for (int p = 0; p < 8; ++p) {
        const int r0 = ((p & ~(M - 1)) << 1) | (p & (M - 1));
        const int r1 = r0 | M;
        float a = xr[r0], b = xr[r1];
        xr[r0] = c * a - s * b;
        xr[r1] = s * a + c * b;
        float u = xi[r0], v = xi[r1];
        xi[r0] = c * u - s * v;
        xi[r1] = s * u + c * v;
    }
}

// CRX with control mask MC, target mask MT (both local): 4 pairs in the control=1 subspace.
// off-diagonal coefficient is -i*s:  r0' = c*r0 + s*q1 ; q0' = c*q0 - s*r1 (validated R1).
template<int MC, int MT>
__device__ __forceinline__ void crx_reg(float (&xr)[16], float (&xi)[16], float c, float s) {
    constexpr int mlo = (MC < MT) ? MC : MT;
    constexpr int mhi = (MC < MT) ? MT : MC;
    #pragma unroll
    for (int p = 0; p < 4; ++p) {
        int q = ((p & ~(mlo - 1)) << 1) | (p & (mlo - 1));
        q     = ((q & ~(mhi - 1)) << 1) | (q & (mhi - 1));
        const int r0 = q | MC;
        const int r1 = r0 | MT;
        float ar = xr[r0], br = xr[r1], ai = xi[r0], bi = xi[r1];
        xr[r0] = c * ar + s * bi;
        xi[r0] = c * ai - s * br;
        xr[r1] = c * br + s * ai;
        xi[r1] = c * bi - s * ar;
    }
}

// Change localization: write regs at rotation kold into swizzled canonical LDS,
// read back at rotation knew. Leading barrier guards WAR vs previous epoch's reads.
__device__ __forceinline__ void restage(float2* lds, float (&xr)[16], float (&xi)[16],
                                        int tb, int kold, int knew) {
    __syncthreads();
    #pragma unroll
    for (int r = 0; r < 16; ++r)
        lds[swz(rotl12(tb | r, kold))] = make_float2(xr[r], xi[r]);
    __syncthreads();
    #pragma unroll
    for (int r = 0; r < 16; ++r) {
        float2 v = lds[swz(rotl12(tb | r, knew))];
        xr[r] = v.x; xi[r] = v.y;
    }
}

// RY window: local j=0..3 -> masks 1,2,4,8, angle indices base+a0..a3
#define RY4(a0,a1,a2,a3) \
    ry_reg<1>(xr, xi, cs_s[base+(a0)], sn_s[base+(a0)]); \
    ry_reg<2>(xr, xi, cs_s[base+(a1)], sn_s[base+(a1)]); \
    ry_reg<4>(xr, xi, cs_s[base+(a2)], sn_s[base+(a2)]); \
    ry_reg<8>(xr, xi, cs_s[base+(a3)], sn_s[base+(a3)]);

// Group-1 CRX triplet (ascending bit pattern): local (jc,jt)=(1,0),(2,1),(3,2)
#define CRX3_UP(i0) \
    crx_reg<2,1>(xr, xi, cs_s[base+12+(i0)],   sn_s[base+12+(i0)]); \
    crx_reg<4,2>(xr, xi, cs_s[base+12+(i0)+1], sn_s[base+12+(i0)+1]); \
    crx_reg<8,4>(xr, xi, cs_s[base+12+(i0)+2], sn_s[base+12+(i0)+2]);

// Group-3 CRX triplet (descending bit pattern): local (jc,jt)=(2,3),(1,2),(0,1)
#define CRX3_DN(i0) \
    crx_reg<4,8>(xr, xi, cs_s[base+36+(i0)],   sn_s[base+36+(i0)]); \
    crx_reg<2,4>(xr, xi, cs_s[base+36+(i0)+1], sn_s[base+36+(i0)+1]); \
    crx_reg<1,2>(xr, xi, cs_s[base+36+(i0)+2], sn_s[base+36+(i0)+2]);

__global__ __launch_bounds__(BLK) void ansatz_kernel(
    const float* __restrict__ sre, const float* __restrict__ sim,
    const float* __restrict__ params, float* __restrict__ out) {

    __shared__ float2 lds[DIM];        // swizzled canonical state, 32 KB
    __shared__ float  cs_s[NPAR], sn_s[NPAR];

    const int b   = blockIdx.x;
    const int tid = threadIdx.x;
    const int tb  = tid << 4;

    // coalesced global -> swizzled LDS
    for (int i = tid; i < DIM; i += BLK)
        lds[swz(i)] = make_float2(sre[b * DIM + i], sim[b * DIM + i]);
    for (int i = tid; i < NPAR; i += BLK) {
        float s, c;
        sincosf(0.5f * params[b * NPAR + i], &s, &c);
        cs_s[i] = c; sn_s[i] = s;
    }
    __syncthreads();

    // initial localization: rotation k=3 (canonical bits 3..6 register-local)
    float xr[16], xi[16];
    #pragma unroll
    for (int r = 0; r < 16; ++r) {
        float2 v = lds[swz(rotl12(tb | r, 3))];
        xr[r] = v.x; xi[r] = v.y;
    }

    for (int l = 0; l < 3; ++l) {
        const int base = 48 * l;
        if (l) restage(lds, xr, xi, tb, 1, 3);
        RY4(8, 7, 6, 5)                         // k=3 : RY qubits 8,7,6,5
        restage(lds, xr, xi, tb, 3, 7);
        RY4(4, 3, 2, 1)                         // k=7 : RY qubits 4,3,2,1
        restage(lds, xr, xi, tb, 7, 11);
        RY4(0, 11, 10, 9)                       // k=11: RY qubits 0,11,10,9
        CRX3_UP(0)                              // k=11: CRX g1 i=0,1,2
        restage(lds, xr, xi, tb, 11, 2);
        CRX3_UP(3)                              // k=2 : i=3,4,5
        restage(lds, xr, xi, tb, 2, 5);
        CRX3_UP(6)                              // k=5 : i=6,7,8
        restage(lds, xr, xi, tb, 5, 8);
        CRX3_UP(9)                              // k=8 : i=9,10,11
        RY4(27, 26, 25, 24)                     // k=8 : RY g2 qubits 3,2,1,0
        restage(lds, xr, xi, tb, 8, 0);
        RY4(35, 34, 33, 32)                     // k=0 : RY g2 qubits 11,10,9,8
        restage(lds, xr, xi, tb, 0, 4);
        RY4(31, 30, 29, 28)                     // k=4 : RY g2 qubits 7,6,5,4
        restage(lds, xr, xi, tb, 4, 10);
        CRX3_DN(0)                              // k=10: CRX g3 i=0,1,2
        restage(lds, xr, xi, tb, 10, 7);
        CRX3_DN(3)                              // k=7 : i=3,4,5
        restage(lds, xr, xi, tb, 7, 4);
        CRX3_DN(6)                              // k=4 : i=6,7,8
        restage(lds, xr, xi, tb, 4, 1);
        CRX3_DN(9)                              // k=1 : i=9,10,11
    }

    // final: regs (k=1) -> canonical LDS -> coalesced global store (re,im interleaved)
    __syncthreads();
    #pragma unroll
    for (int r = 0; r < 16; ++r)
        lds[swz(rotl12(tb | r, 1))] = make_float2(xr[r], xi[r]);
    __syncthreads();
    float2* out2 = (float2*)out + (size_t)b * DIM;
    for (int i = tid; i < DIM; i += BLK)
        out2[i] = lds[swz(i)];
}

extern "C" void kernel_launch(void* const* d_in, const int* in_sizes, int n_in,
                              void* d_out, int out_size, void* d_ws, size_t ws_size,
                              hipStream_t stream) {
    const float* sre    = (const float*)d_in[0];
    const float* sim    = (const float*)d_in[1];
    const float* params = (const float*)d_in[2];
    float* out          = (float*)d_out;

    const int B = in_sizes[0] / DIM;   // 128
    ansatz_kernel<<<B, BLK, 0, stream>>>(sre, sim, params, out);
}